// Round 3
// baseline (302.462 us; speedup 1.0000x reference)
//
#include <hip/hip_runtime.h>

namespace {

typedef __attribute__((ext_vector_type(8))) short short8;   // MFMA A/B frag (8 bf16)
typedef __attribute__((ext_vector_type(4))) float floatx4;  // MFMA C/D frag

constexpr int T    = 512;
constexpr int H    = 64;
constexpr int TPB  = 1024;  // 16 waves = 4/SIMD: cross-wave stall coverage (R25)
constexpr int MB   = 8;     // grid 256 -> 1 block/CU, all CUs
constexpr int HST  = 128;   // ushorts per bat row, EXACT (rotation-swizzled, no pad)
constexpr int XSTR = 516;   // xs row stride (floats)
constexpr int FSTR = 68;    // hf32 row stride (floats, head only)

constexpr int DPP_ROR8 = 0x128;  // row_ror:8 -> lane i reads lane i^8 (within row of 16)

__device__ __forceinline__ ushort f2bf(float x) {  // fp32 -> bf16 RN-even (finite)
  unsigned u = __float_as_uint(x);
  unsigned r = u + 0x7fffu + ((u >> 16) & 1u);
  return (ushort)(r >> 16);
}
__device__ __forceinline__ float bf2f(ushort h) {
  return __uint_as_float(((unsigned)h) << 16);
}
__device__ __forceinline__ float fsig(float x) {
  return __builtin_amdgcn_rcpf(1.0f + __expf(-x));
}
__device__ __forceinline__ float ftanh(float x) {
  return fmaf(-2.0f, __builtin_amdgcn_rcpf(1.0f + __expf(2.0f * x)), 1.0f);
}
__device__ __forceinline__ float swz8(float v) {   // value from lane^8 (row of 16), VALU pipe
  return __int_as_float(__builtin_amdgcn_update_dpp(
      0, __float_as_int(v), DPP_ROR8, 0xf, 0xf, true));
}

// R25 (resubmit; R2 bench was a GPUAcquisitionTimeout, never ran).
// 16-wave 1-tile topology with ty-pair gate split.
// R24 post-mortem: co-resident blocks do NOT de-phase (265 us; MFMA doubling
// paid in full, zero stall recovery). The ~330-400 cyc in-phase chain stall
// must be covered WITHIN one workgroup -> 4 waves/SIMD (TPB=1024, 1 tile/wave).
// The ty-column duplication (lanes l and l^8 share one (unit,bat) after the
// symmetric d+swz8(d) combine) is harvested, not wasted:
//   - combine loses both cndmasks: p = d + swz8(d) + fma (was 6 ops -> 4)
//   - gate split: ty0 evals sig(p0),sig(p1); ty1 evals tanh(p2),sig(p3) via a
//     unified fmaf(m, rcp(1+exp(p*s)), a) with per-lane (s,m,a); tanh(c)
//     shared. Transcendentals 10 -> 6 instr/lane (quarter-rate pipe).
//   - h writes 2 -> 1 per lane (ty0 hi, ty1 lo); 3 extra DPP exchanges.
// Per-wave issue ~halves; per-SIMD issue ~= R23; 4 staggered chains/SIMD
// cover each other's ds_read->MFMA->exp latency.
// True-path arithmetic is BIT-IDENTICAL to R23 (same fsig/ftanh/c order,
// trunc split) -> absmax must reproduce 3.05e-5.
__global__ __launch_bounds__(TPB, 4)
void lstm_mfma(const float* __restrict__ xg,
               const float* __restrict__ W_ih,
               const float* __restrict__ W_hh,
               const float* __restrict__ b_ih,
               const float* __restrict__ b_hh,
               const float* __restrict__ fc1_w,
               const float* __restrict__ fc1_b,
               const float* __restrict__ fc2_w,
               const float* __restrict__ fc2_b,
               float* __restrict__ out)
{
  __shared__ __align__(16) ushort hA[MB * HST];   // h double-buffer (rot-swizzled rows)
  __shared__ __align__(16) ushort hB[MB * HST];
  __shared__ __align__(16) float  xs[MB * XSTR];
  __shared__ __align__(16) float  hf[MB * FSTR];  // final h fp32 (head; written once)
  __shared__ float zs[MB][16];

  const int tid  = threadIdx.x;
  const int b0   = blockIdx.x * MB;
  const int lane = tid & 63;
  const int wj   = tid >> 6;       // wave 0..15 -> tile wj (units 4wj..4wj+3)
  const int n    = lane & 15;      // MFMA col: batch n&7, type n>>3 (0=hi,1=lo)
  const int kg   = lane >> 4;      // k-group (A/B), row-quad (D)
  const int bat  = n & 7;
  const int ty   = n >> 3;
  const int rot  = 24 * bat;       // per-bat rotation (ushorts; mult of 8 -> 16B-aligned)

  // ---- stage x (coalesced float4) ----
  for (int i = tid; i < MB * T / 4; i += TPB) {
    const int xb = i >> 7, tq = i & 127;
    float4 v = ((const float4*)(xg + (size_t)(b0 + xb) * T))[tq];
    *(float4*)&xs[xb * XSTR + tq * 4] = v;
  }
  // ---- zero h buffers (h0 = 0) ----
  for (int i = tid; i < MB * HST; i += TPB) { hA[i] = 0; hB[i] = 0; }

  // ---- A-frags for tile wj (gate-interleaved permutation, verified R12) ----
  short8 whi[2], wlo[2];           // [k-half]
  {
    const int arow = 64 * (n & 3) + 4 * wj + (n >> 2);  // gate n&3, local unit n>>2
    const float* wr = W_hh + arow * H + 8 * kg;
    const float4 p0 = *(const float4*)(wr + 0);
    const float4 p1 = *(const float4*)(wr + 4);
    const float4 p2 = *(const float4*)(wr + 32);
    const float4 p3 = *(const float4*)(wr + 36);
    const float v0[8] = {p0.x, p0.y, p0.z, p0.w, p1.x, p1.y, p1.z, p1.w};
    const float v1[8] = {p2.x, p2.y, p2.z, p2.w, p3.x, p3.y, p3.z, p3.w};
#pragma unroll
    for (int j = 0; j < 8; ++j) {
      const ushort h0 = f2bf(v0[j]);
      whi[0][j] = (short)h0;
      wlo[0][j] = (short)f2bf(v0[j] - bf2f(h0));   // exact remainder, then RN
      const ushort h1 = f2bf(v1[j]);
      whi[1][j] = (short)h1;
      wlo[1][j] = (short)f2bf(v1[j] - bf2f(h1));
    }
  }

  // ---- owned state: unit u = 4wj + kg, batch bat; ty pair shares (u,bat) ----
  const int u = 4 * wj + kg;
  float bia[4], wih[4];
#pragma unroll
  for (int j = 0; j < 4; ++j) {                 // gate rows: i,f,g,o = 64j + u
    const int row = 64 * j + u;
    bia[j] = b_ih[row] + b_hh[row];
    wih[j] = W_ih[row];
  }

  // ---- per-lane unified-gate parameters (ty0: f=sig, ty1: g=tanh) ----
  const float s2  = ty ? 2.0f : -1.0f;   // exp argument scale
  const float mqb = ty ? -2.0f : 1.0f;   // tanh = fmaf(-2, t, 1); sig = t
  const float aqb = ty ? 1.0f : 0.0f;

  // ---- swizzled LDS offsets (precomputed; rotation wrap => separate mods) ----
  const int rd0  = bat * HST + ((64 * ty + 8 * kg + rot) & 127);       // f0 (k 0..31)
  const int rd1  = bat * HST + ((64 * ty + 8 * kg + 32 + rot) & 127);  // f1 (k 32..63)
  const int wr_o = bat * HST + ((u + 64 * ty + rot) & 127);            // hi (ty0) / lo (ty1)
  const float* xq = &xs[bat * XSTR];
  float c = 0.0f, hlast = 0.0f;

  __syncthreads();

#define STEP(HR, HW, XT)                                                       \
  {                                                                            \
    const short8 f0 = *(const short8*)((HR) + rd0);                            \
    const short8 f1 = *(const short8*)((HR) + rd1);                            \
    const floatx4 zf = {0.f, 0.f, 0.f, 0.f};                                   \
    /* single 4-deep chain; cross-wave (4/SIMD) covers its latency */          \
    floatx4 d = __builtin_amdgcn_mfma_f32_16x16x32_bf16(whi[0], f0, zf, 0, 0, 0); \
    d = __builtin_amdgcn_mfma_f32_16x16x32_bf16(wlo[0], f0, d, 0, 0, 0);       \
    d = __builtin_amdgcn_mfma_f32_16x16x32_bf16(whi[1], f1, d, 0, 0, 0);       \
    d = __builtin_amdgcn_mfma_f32_16x16x32_bf16(wlo[1], f1, d, 0, 0, 0);       \
    float p[4];                                                                \
    _Pragma("unroll") for (int j = 0; j < 4; ++j) {                            \
      /* symmetric combine: lane^8 holds the other h-type col of MY tile */    \
      p[j] = d[j] + swz8(d[j]) + fmaf((XT), wih[j], bia[j]);                   \
    }                                                                          \
    /* ty-split gates: ty0 -> i=sig(p0), f=sig(p1); ty1 -> o=sig(p3), g=tanh(p2) */ \
    const float pa = ty ? p[3] : p[0];                                         \
    const float pb = ty ? p[2] : p[1];                                         \
    const float qa = fsig(pa);                                                 \
    const float tb = __builtin_amdgcn_rcpf(1.0f + __expf(pb * s2));            \
    const float qb = fmaf(mqb, tb, aqb);                                       \
    /* c valid at ty0: c = f*c + i*g  (g pulled from ty1) */                   \
    c = fmaf(qb, c, qa * swz8(qb));                                            \
    /* h valid at ty0: h = o*tanh(c)  (o pulled from ty1) */                   \
    const float hk0 = swz8(qa) * ftanh(c);                                     \
    const float hkx = swz8(hk0);                                               \
    const float hku = ty ? hkx : hk0;   /* true h at BOTH lanes */             \
    const ushort hib = (ushort)(__float_as_uint(hku) >> 16);  /* trunc hi */   \
    const float  rem = hku - bf2f(hib);                                        \
    const ushort rus = (ushort)(__float_as_uint(rem) >> 16);  /* trunc lo */   \
    (HW)[wr_o] = ty ? rus : hib;        /* one b16 write per lane */           \
    hlast = hku;                                                               \
    __syncthreads();                                                           \
  }

  for (int t = 0; t < T; t += 2) {
    const float2 x2 = *(const float2*)(xq + t);   // one b64 read feeds both steps
    STEP(hA, hB, x2.x);
    STEP(hB, hA, x2.y);
  }
#undef STEP

  // ---- final h (fp32) -> LDS once (ty pair writes same value; benign) ----
  hf[bat * FSTR + u] = hlast;
  __syncthreads();
  if (tid < MB * 16) {
    const int bq = tid >> 4, j2 = tid & 15;   // 8 batches x 16 hidden2
    float s = fc1_b[j2];
    const float* fw = fc1_w + j2 * H;
#pragma unroll
    for (int k = 0; k < H; ++k) s = fmaf(hf[bq * FSTR + k], fw[k], s);
    s = fmaxf(s, 0.0f);
    zs[bq][j2] = s * fc2_w[j2];
  }
  __syncthreads();
  if (tid < MB) {
    float s = fc2_b[0];
#pragma unroll
    for (int j = 0; j < 16; ++j) s += zs[tid][j];
    out[b0 + tid] = s;
  }
}

}  // namespace

extern "C" void kernel_launch(void* const* d_in, const int* in_sizes, int n_in,
                              void* d_out, int out_size, void* d_ws, size_t ws_size,
                              hipStream_t stream) {
  const float* xg    = (const float*)d_in[0];
  const float* W_ih  = (const float*)d_in[1];
  const float* W_hh  = (const float*)d_in[2];
  const float* b_ih  = (const float*)d_in[3];
  const float* b_hh  = (const float*)d_in[4];
  const float* fc1_w = (const float*)d_in[5];
  const float* fc1_b = (const float*)d_in[6];
  const float* fc2_w = (const float*)d_in[7];
  const float* fc2_b = (const float*)d_in[8];
  float* out = (float*)d_out;

  dim3 grid(2048 / MB);   // 256 blocks -> 1 per CU, 16 waves = 4/SIMD
  dim3 block(TPB);
  hipLaunchKernelGGL(lstm_mfma, grid, block, 0, stream,
                     xg, W_ih, W_hh, b_ih, b_hh, fc1_w, fc1_b, fc2_w, fc2_b, out);
}